// Round 5
// baseline (107.484 us; speedup 1.0000x reference)
//
#include <hip/hip_runtime.h>
#include <math.h>

// VQ quantizer: x [512,256,12] fp32, codebook [512,12] fp32.
// Outputs (concat fp32): quantized_st [512*256*12], indices-as-float [512*256], loss [1].
//
// R12: R7/R10/R11 all plateaued at ~46us with VALUBusy 43/38/62%. R7/R10's
// VALU-time equals the issue floor (stall-bound); R11 removed stalls but at
// 4 waves/SIMD (grid supplies 16 waves/CU) the SIMD still idles 38%.
// VGPR=64 sits exactly at the 8-waves/SIMD tier edge -- the grid, not the
// tier, is the cap. Fix: TPT=2 halves xs (VGPR ~55) AND doubles the grid:
// 1024 blocks x 8 waves = 8192 waves = 32/CU = 8/SIMD. Issue floor rises
// 17.3->20us (13 broadcasts now amortized over 2 tokens), but 8-deep wave
// overlap should convert ~17us of measured idle into overlap.
// Inner loop still touches NO memory: lane-sharded codebook (lane l of wave
// s holds code s*64+l in 13 VGPRs), v_readlane broadcast, explicit 2-code
// double-buffer so each batch of readlanes flies under the previous code's
// 34-instr score window. launch_bounds(512,4) remains a CAP (R8 lesson).
namespace {
constexpr int KCB   = 512;
constexpr int DIM   = 12;
constexpr int NTOK  = 512 * 256;       // 131072
constexpr int QSIZE = NTOK * DIM;      // 1572864
constexpr int NSPLIT = 8;              // waves per block == K chunks
constexpr int KCHUNK = KCB / NSPLIT;   // 64 codes per wave == 64 lanes
constexpr int TPT    = 2;              // tokens/thread (VGPR <= 64 => 8 waves/SIMD)
constexpr int TOKS_PER_BLOCK = 64 * TPT;        // 128
constexpr int NBLK   = NTOK / TOKS_PER_BLOCK;   // 1024 blocks x 512 thr

// u64 (monotone(score), k) unsigned-min == exact lexicographic
// first-occurrence argmin (validated R2-R11).
__device__ inline unsigned long long mkkey(float v, int k) {
    unsigned su = __float_as_uint(v);
    su = (su & 0x80000000u) ? ~su : (su | 0x80000000u);
    return ((unsigned long long)su << 32) | (unsigned)k;
}

__device__ inline float bcast(float v, int lane) {
    return __uint_as_float(__builtin_amdgcn_readlane(__float_as_uint(v), lane));
}

// zero the loss accumulator (stream-ordered before vq_main's atomics;
// re-runs every replay after harness re-poisoning).
__global__ void init_loss(float* __restrict__ out) {
    if (threadIdx.x == 0) out[QSIZE + NTOK] = 0.f;
}

// Block = 128 tokens x 8 K-splits. Codebook chunk lane-sharded in VGPRs;
// inner loop touches NO memory. LDS only for the 8 KB cross-wave key reduce.
__global__ __launch_bounds__(512, 4) void vq_main(const float* __restrict__ x,
                                                  const float* __restrict__ cb,
                                                  float* __restrict__ out) {
    __shared__ unsigned long long keys[NSPLIT * TOKS_PER_BLOCK];  // 8 KB
    __shared__ float lred[TPT];
    const int tid  = threadIdx.x;
    const int lane = tid & 63;
    const int s = __builtin_amdgcn_readfirstlane(tid >> 6);  // K-chunk id
    const int tbase = blockIdx.x * TOKS_PER_BLOCK;

    // lane's code: kc = s*64 + lane. Row -> 13 VGPRs; w2 via the EXACT
    // fmaf chain previously validated (bit-identical per code).
    float cw[13];
    {
        const int kc = (s << 6) + lane;
        const float4* wp = (const float4*)(cb + (size_t)kc * DIM);
        float4 c0 = wp[0], c1 = wp[1], c2 = wp[2];
        cw[0] = c0.x; cw[1] = c0.y; cw[2]  = c0.z; cw[3]  = c0.w;
        cw[4] = c1.x; cw[5] = c1.y; cw[6]  = c1.z; cw[7]  = c1.w;
        cw[8] = c2.x; cw[9] = c2.y; cw[10] = c2.z; cw[11] = c2.w;
        float w2 = 0.f;
#pragma unroll
        for (int d = 0; d < DIM; ++d) w2 = fmaf(cw[d], cw[d], w2);
        cw[12] = w2;
    }

    // this thread's 2 tokens (lane-contiguous 48B rows)
    float xs[TPT][DIM];
    float x2[TPT];
#pragma unroll
    for (int j = 0; j < TPT; ++j) {
        const float4* xp = (const float4*)(x + (size_t)(tbase + j * 64 + lane) * DIM);
        float4 a0 = xp[0], a1 = xp[1], a2 = xp[2];
        xs[j][0] = a0.x; xs[j][1] = a0.y; xs[j][2]  = a0.z; xs[j][3]  = a0.w;
        xs[j][4] = a1.x; xs[j][5] = a1.y; xs[j][6]  = a1.z; xs[j][7]  = a1.w;
        xs[j][8] = a2.x; xs[j][9] = a2.y; xs[j][10] = a2.z; xs[j][11] = a2.w;
        float t2 = 0.f;
#pragma unroll
        for (int d = 0; d < DIM; ++d) t2 = fmaf(xs[j][d], xs[j][d], t2);
        x2[j] = t2;
    }

    float best[TPT];
    int   bi[TPT];
#pragma unroll
    for (int j = 0; j < TPT; ++j) { best[j] = INFINITY; bi[j] = 0; }

    const int k0 = s << 6;   // global code id of chunk start

    // ---- inner loop: pure registers, 2-code broadcast double-buffer.
    // kk ascending => strict < keeps first occurrence in global-k order
    // (EXACT semantics of R1-R11). wA/wB are wave-uniform -> SGPR-resident.
    float wA[13], wB[13];
#pragma unroll
    for (int d = 0; d < 13; ++d) wA[d] = bcast(cw[d], 0);
#pragma unroll 4
    for (int kk = 0; kk < KCHUNK; kk += 2) {
        // prefetch odd code kk+1 into wB (flies under A's score window)
#pragma unroll
        for (int d = 0; d < 13; ++d) wB[d] = bcast(cw[d], kk + 1);
        {   // score even code kk with A
            const int k = k0 + kk;
#pragma unroll
            for (int j = 0; j < TPT; ++j) {
                // EXACT score sequence validated R1-R11. Do not reorder.
                float xw = 0.f;
                xw = fmaf(xs[j][0],  wA[0],  xw);
                xw = fmaf(xs[j][1],  wA[1],  xw);
                xw = fmaf(xs[j][2],  wA[2],  xw);
                xw = fmaf(xs[j][3],  wA[3],  xw);
                xw = fmaf(xs[j][4],  wA[4],  xw);
                xw = fmaf(xs[j][5],  wA[5],  xw);
                xw = fmaf(xs[j][6],  wA[6],  xw);
                xw = fmaf(xs[j][7],  wA[7],  xw);
                xw = fmaf(xs[j][8],  wA[8],  xw);
                xw = fmaf(xs[j][9],  wA[9],  xw);
                xw = fmaf(xs[j][10], wA[10], xw);
                xw = fmaf(xs[j][11], wA[11], xw);
                float d = fmaf(-2.f, xw, x2[j]) + wA[12];
                bool c = d < best[j];          // strict < => first occurrence
                best[j] = c ? d : best[j];
                bi[j]   = c ? k : bi[j];
            }
        }
        // prefetch next even code kk+2 into wA ((kk+2)&63 wraps to lane 0 on
        // the final iteration: loaded but never scored)
#pragma unroll
        for (int d = 0; d < 13; ++d) wA[d] = bcast(cw[d], (kk + 2) & 63);
        {   // score odd code kk+1 with B
            const int k = k0 + kk + 1;
#pragma unroll
            for (int j = 0; j < TPT; ++j) {
                float xw = 0.f;
                xw = fmaf(xs[j][0],  wB[0],  xw);
                xw = fmaf(xs[j][1],  wB[1],  xw);
                xw = fmaf(xs[j][2],  wB[2],  xw);
                xw = fmaf(xs[j][3],  wB[3],  xw);
                xw = fmaf(xs[j][4],  wB[4],  xw);
                xw = fmaf(xs[j][5],  wB[5],  xw);
                xw = fmaf(xs[j][6],  wB[6],  xw);
                xw = fmaf(xs[j][7],  wB[7],  xw);
                xw = fmaf(xs[j][8],  wB[8],  xw);
                xw = fmaf(xs[j][9],  wB[9],  xw);
                xw = fmaf(xs[j][10], wB[10], xw);
                xw = fmaf(xs[j][11], wB[11], xw);
                float d = fmaf(-2.f, xw, x2[j]) + wB[12];
                bool c = d < best[j];
                best[j] = c ? d : best[j];
                bi[j]   = c ? k : bi[j];
            }
        }
    }

    // cross-wave argmin via u64 keys in LDS (global code ids 0..511)
#pragma unroll
    for (int j = 0; j < TPT; ++j)
        keys[s * TOKS_PER_BLOCK + j * 64 + lane] = mkkey(best[j], bi[j]);
    __syncthreads();

    // waves 0..1 finalize token group j==s (they hold xs[s] for those tokens)
    if (s < TPT) {
        const int tok = s * 64 + lane;
        unsigned long long m = keys[tok];
#pragma unroll
        for (int r = 1; r < NSPLIT; ++r) {
            unsigned long long v = keys[r * TOKS_PER_BLOCK + tok];
            m = v < m ? v : m;
        }
        const int bid = (int)(m & 0xffffffffULL);
        unsigned eu = (unsigned)(m >> 32);
        unsigned orig = (eu & 0x80000000u) ? (eu ^ 0x80000000u) : ~eu;
        const float bsc = __uint_as_float(orig);
        const int t = tbase + tok;

        float xv[DIM];
#pragma unroll
        for (int j = 0; j < TPT; ++j)
            if (j == s) {
#pragma unroll
                for (int d = 0; d < DIM; ++d) xv[d] = xs[j][d];
            }

        const float4* wrow = (const float4*)(cb + (size_t)bid * DIM);
        float4 q0 = wrow[0], q1 = wrow[1], q2 = wrow[2];
        float qs[DIM] = {q0.x, q0.y, q0.z, q0.w, q1.x, q1.y, q1.z, q1.w,
                         q2.x, q2.y, q2.z, q2.w};

        float4* qo = (float4*)(out + (size_t)t * DIM);
        float4 r0, r1, r2;
        r0.x = xv[0] + (qs[0] - xv[0]);    r0.y = xv[1] + (qs[1] - xv[1]);
        r0.z = xv[2] + (qs[2] - xv[2]);    r0.w = xv[3] + (qs[3] - xv[3]);
        r1.x = xv[4] + (qs[4] - xv[4]);    r1.y = xv[5] + (qs[5] - xv[5]);
        r1.z = xv[6] + (qs[6] - xv[6]);    r1.w = xv[7] + (qs[7] - xv[7]);
        r2.x = xv[8] + (qs[8] - xv[8]);    r2.y = xv[9] + (qs[9] - xv[9]);
        r2.z = xv[10] + (qs[10] - xv[10]); r2.w = xv[11] + (qs[11] - xv[11]);
        qo[0] = r0; qo[1] = r1; qo[2] = r2;

        out[QSIZE + t] = (float)bid;

        // loss partial: sum_d(q-x)^2 == best score (~1e-8 rel; thr ~2%).
        float ls = bsc * (1.25f / (float)QSIZE);
#pragma unroll
        for (int off = 32; off > 0; off >>= 1) ls += __shfl_down(ls, off);
        if (lane == 0) lred[s] = ls;
    }
    __syncthreads();
    // one fp32 atomic per block (accumulator zeroed by init_loss; order
    // reassociation ~1e-7 rel, far under the ~2% loss threshold)
    if (tid == 0) atomicAdd(out + QSIZE + NTOK, lred[0] + lred[1]);
}
} // namespace

extern "C" void kernel_launch(void* const* d_in, const int* in_sizes, int n_in,
                              void* d_out, int out_size, void* d_ws, size_t ws_size,
                              hipStream_t stream) {
    const float* x  = (const float*)d_in[0];
    const float* cb = (const float*)d_in[1];
    float* out = (float*)d_out;
    (void)d_ws; (void)ws_size;

    init_loss<<<1, 64, 0, stream>>>(out);
    vq_main<<<NBLK, 512, 0, stream>>>(x, cb, out);
}

// Round 9
// 104.283 us; speedup vs baseline: 1.0307x; 1.0307x over previous
//
#include <hip/hip_runtime.h>
#include <math.h>

// VQ quantizer: x [512,256,12] fp32, codebook [512,12] fp32.
// Outputs (concat fp32): quantized_st [512*256*12], indices-as-float [512*256], loss [1].
//
// R16: the asm ds_read path (R13-R15) is condemned (two identical rare key
// corruptions, un-localizable). Re-derivation of all passing rounds:
//   - LDS uniform broadcast pays FULL fan-out (64 lanes x 16B through the
//     ~112 B/cy LDS pipe ~9cy/b128): R7's wall = 16 waves x 4 DS/code
//     ~ 420 cy/code-round == measured 422. LDS-BW-bound, not wait-bound.
//   - v_readlane pays the same toll on the VALU port (~8cy): R11/R12.
//   - SGPR operands broadcast FREE inside v_fma: R10 (s_load->SGPR) was
//     bit-exact and sat AT the VALU issue floor; its wall was K$ stalls
//     (8 divergent streams, only 4 waves/SIMD to cover them).
// Fix R10's occupancy+locality, keep its VALIDATED asm contract:
//   KSPLIT=4 chunks x TPT=1 -> VGPR ~32 (<=64 tier) -> 8 waves/SIMD;
//   2048 blocks x 4 waves = 32 waves/CU exactly; 4 shared code streams/CU
//   (K$/L2-coherent). Every s_waitcnt is lgkmcnt(0) (full drain, one load
//   outstanding, 34-VALU cover; SMEM out-of-order safe). Loop peeled: ZERO
//   in-flight ops at loop exit (R14 lesson). Tied "+s"(f32x16) on the wait
//   gives the dataflow edge that orders the FMA consumers (R10-proven).
namespace {
constexpr int KCB   = 512;
constexpr int DIM   = 12;
constexpr int NTOK  = 512 * 256;       // 131072
constexpr int QSIZE = NTOK * DIM;      // 1572864
constexpr int KSPLIT = 4;              // waves per block == K chunks
constexpr int KCHUNK = KCB / KSPLIT;   // 128 codes per wave
constexpr int TPB    = 256;            // 4 waves, 64 tokens/block (TPT=1)
constexpr int NBLK   = NTOK / 64;      // 2048 blocks
constexpr int ROWF   = 16;             // packed row: w[12], w2, pad[3] (64 B)
constexpr int PARTIALS_OFF = 16384;    // float offset of partials in ws (pk=8K floats)

typedef __attribute__((ext_vector_type(16))) float f32x16;

// u64 (monotone(score), k) unsigned-min == exact lexicographic
// first-occurrence argmin (validated R2-R12).
__device__ inline unsigned long long mkkey(float v, int k) {
    unsigned su = __float_as_uint(v);
    su = (su & 0x80000000u) ? ~su : (su | 0x80000000u);
    return ((unsigned long long)su << 32) | (unsigned)k;
}

// Pack codebook into 64 B rows [w0..w11, w2, 0,0,0] (w2 = EXACT fmaf chain,
// same rounding as R1-R12).
__global__ __launch_bounds__(256) void pack_cb(const float* __restrict__ cb,
                                               float* __restrict__ pk) {
    int k = blockIdx.x * blockDim.x + threadIdx.x;
    if (k >= KCB) return;
    float w[DIM];
#pragma unroll
    for (int d = 0; d < DIM; ++d) w[d] = cb[k * DIM + d];
    float w2 = 0.f;
#pragma unroll
    for (int d = 0; d < DIM; ++d) w2 = fmaf(w[d], w[d], w2);
#pragma unroll
    for (int d = 0; d < DIM; ++d) pk[k * ROWF + d] = w[d];
    pk[k * ROWF + 12] = w2;
    pk[k * ROWF + 13] = 0.f; pk[k * ROWF + 14] = 0.f; pk[k * ROWF + 15] = 0.f;
}

// EXACT score sequence validated R1-R12 (one SGPR operand per v_fma). TPT=1.
#define SCORE_CODE(R, KIDX)                                                  \
    {                                                                        \
        const int kq_ = (KIDX);                                              \
        float xw = 0.f;                                                      \
        xw = fmaf(xs[0],  (R)[0],  xw);                                      \
        xw = fmaf(xs[1],  (R)[1],  xw);                                      \
        xw = fmaf(xs[2],  (R)[2],  xw);                                      \
        xw = fmaf(xs[3],  (R)[3],  xw);                                      \
        xw = fmaf(xs[4],  (R)[4],  xw);                                      \
        xw = fmaf(xs[5],  (R)[5],  xw);                                      \
        xw = fmaf(xs[6],  (R)[6],  xw);                                      \
        xw = fmaf(xs[7],  (R)[7],  xw);                                      \
        xw = fmaf(xs[8],  (R)[8],  xw);                                      \
        xw = fmaf(xs[9],  (R)[9],  xw);                                      \
        xw = fmaf(xs[10], (R)[10], xw);                                      \
        xw = fmaf(xs[11], (R)[11], xw);                                      \
        float dq = fmaf(-2.f, xw, x2) + (R)[12];                             \
        bool cq = dq < best;         /* strict < => first occurrence */      \
        best = cq ? dq : best;                                               \
        bi   = cq ? kq_ : bi;                                                \
    }

// R10-validated scalar asm: issue one 64B row into an SGPR 16-tuple.
#define SISSUE(R, ADDR)                                                      \
    asm volatile("s_load_dwordx16 %0, %1, 0" : "=s"(R) : "s"(ADDR));
// R10-validated wait: full drain; tied "+s" tuple = dataflow edge ordering
// all consumers of R after the wait (compiles for SCALAR tuples).
#define SWAIT(R)                                                             \
    asm volatile("s_waitcnt lgkmcnt(0)" : "+s"(R));

// Block = 64 tokens x 4 K-chunks (wave w scans codes [w*128, (w+1)*128)).
// Codebook rows stream L2->K$->SGPRs; LDS only for the 2 KB key reduce.
__global__ __launch_bounds__(256, 4) void vq_main(const float* __restrict__ x,
                                                  const float* __restrict__ cb,
                                                  const float* __restrict__ pk,
                                                  float* __restrict__ out,
                                                  float* __restrict__ partials) {
    __shared__ unsigned long long keys[KSPLIT * 64];   // 2 KB
    const int tid  = threadIdx.x;
    const int lane = tid & 63;
    const int w = __builtin_amdgcn_readfirstlane(tid >> 6);  // K-chunk id
    const int tok = blockIdx.x * 64 + lane;   // every wave holds the same 64 tokens

    // this thread's token (48 B row, 16B-aligned)
    float xs[DIM];
    float x2;
    {
        const float4* xp = (const float4*)(x + (size_t)tok * DIM);
        float4 a0 = xp[0], a1 = xp[1], a2 = xp[2];
        xs[0] = a0.x; xs[1] = a0.y; xs[2]  = a0.z; xs[3]  = a0.w;
        xs[4] = a1.x; xs[5] = a1.y; xs[6]  = a1.z; xs[7]  = a1.w;
        xs[8] = a2.x; xs[9] = a2.y; xs[10] = a2.z; xs[11] = a2.w;
        float t2 = 0.f;
#pragma unroll
        for (int d = 0; d < DIM; ++d) t2 = fmaf(xs[d], xs[d], t2);
        x2 = t2;
    }

    float best = INFINITY;
    int   bi = 0;

    const int k0 = w * KCHUNK;
    const unsigned long long base =
        (unsigned long long)(uintptr_t)(pk + (size_t)k0 * ROWF);

    f32x16 A, B;
    SISSUE(A, base);                       // prologue: one load in flight
    for (int kk = 0; kk < KCHUNK - 2; kk += 2) {
        SWAIT(A);                          // A ready (drain; only A was out)
        SISSUE(B, base + (unsigned long long)((kk + 1) * 64));
        SCORE_CODE(A, k0 + kk);            // 17 VALU cover B's flight
        SWAIT(B);                          // B ready (only B was out)
        SISSUE(A, base + (unsigned long long)((kk + 2) * 64));
        SCORE_CODE(B, k0 + kk + 1);
    }
    // peeled tail: codes KCHUNK-2, KCHUNK-1; no reissue => ZERO in-flight
    // SMEM ops after this point (no async writeback into reused SGPRs).
    SWAIT(A);
    SISSUE(B, base + (unsigned long long)((KCHUNK - 1) * 64));
    SCORE_CODE(A, k0 + KCHUNK - 2);
    SWAIT(B);
    SCORE_CODE(B, k0 + KCHUNK - 1);

    // cross-wave argmin via u64 keys in LDS (global code ids 0..511)
    keys[w * 64 + lane] = mkkey(best, bi);
    __syncthreads();

    // wave 0 finalizes (it holds the same xs for these 64 tokens)
    if (tid < 64) {
        unsigned long long m = keys[lane];
#pragma unroll
        for (int r = 1; r < KSPLIT; ++r) {
            unsigned long long v = keys[r * 64 + lane];
            m = v < m ? v : m;
        }
        const int bid = (int)(m & 0xffffffffULL);
        unsigned eu = (unsigned)(m >> 32);
        unsigned orig = (eu & 0x80000000u) ? (eu ^ 0x80000000u) : ~eu;
        const float bsc = __uint_as_float(orig);

        const float4* wrow = (const float4*)(cb + (size_t)bid * DIM);
        float4 q0 = wrow[0], q1 = wrow[1], q2 = wrow[2];
        float qs[DIM] = {q0.x, q0.y, q0.z, q0.w, q1.x, q1.y, q1.z, q1.w,
                         q2.x, q2.y, q2.z, q2.w};

        float4* qo = (float4*)(out + (size_t)tok * DIM);
        float4 r0, r1, r2;
        r0.x = xs[0] + (qs[0] - xs[0]);    r0.y = xs[1] + (qs[1] - xs[1]);
        r0.z = xs[2] + (qs[2] - xs[2]);    r0.w = xs[3] + (qs[3] - xs[3]);
        r1.x = xs[4] + (qs[4] - xs[4]);    r1.y = xs[5] + (qs[5] - xs[5]);
        r1.z = xs[6] + (qs[6] - xs[6]);    r1.w = xs[7] + (qs[7] - xs[7]);
        r2.x = xs[8] + (qs[8] - xs[8]);    r2.y = xs[9] + (qs[9] - xs[9]);
        r2.z = xs[10] + (qs[10] - xs[10]); r2.w = xs[11] + (qs[11] - xs[11]);
        qo[0] = r0; qo[1] = r1; qo[2] = r2;

        out[QSIZE + tok] = (float)bid;

        // loss partial: sum_d(q-x)^2 == best score (~1e-8 rel; thr ~2%).
        float ls = bsc * (1.25f / (float)QSIZE);
#pragma unroll
        for (int off = 32; off > 0; off >>= 1) ls += __shfl_down(ls, off);
        if (lane == 0) partials[blockIdx.x] = ls;
    }
}

// 2048 partials -> loss, single block, no atomics (stream-ordered after
// vq_main; re-runs on every replay).
__global__ __launch_bounds__(512) void reduce_loss(const float* __restrict__ partials,
                                                   float* __restrict__ out) {
    __shared__ float r[8];
    float v = (partials[threadIdx.x]        + partials[threadIdx.x + 512])
            + (partials[threadIdx.x + 1024] + partials[threadIdx.x + 1536]);
#pragma unroll
    for (int off = 32; off > 0; off >>= 1) v += __shfl_down(v, off);
    if ((threadIdx.x & 63) == 0) r[threadIdx.x >> 6] = v;
    __syncthreads();
    if (threadIdx.x == 0) {
        float t = 0.f;
#pragma unroll
        for (int i = 0; i < 8; ++i) t += r[i];
        out[QSIZE + NTOK] = t;
    }
}
} // namespace

extern "C" void kernel_launch(void* const* d_in, const int* in_sizes, int n_in,
                              void* d_out, int out_size, void* d_ws, size_t ws_size,
                              hipStream_t stream) {
    const float* x  = (const float*)d_in[0];
    const float* cb = (const float*)d_in[1];
    float* out = (float*)d_out;
    float* pk  = (float*)d_ws;                      // packed codebook (32 KB)
    float* partials = (float*)d_ws + PARTIALS_OFF;  // 2048 block partials

    pack_cb<<<2, 256, 0, stream>>>(cb, pk);
    vq_main<<<NBLK, TPB, 0, stream>>>(x, cb, pk, out, partials);
    reduce_loss<<<1, 512, 0, stream>>>(partials, out);
}